// Round 10
// baseline (138.207 us; speedup 1.0000x reference)
//
#include <hip/hip_runtime.h>
#include <hip/hip_bf16.h>

#define NB 64
#define CD 128
#define LL 4096
#define LCHUNK 64
#define NCHUNK 64      // LL/LCHUNK

typedef __attribute__((ext_vector_type(8))) short short8;
typedef __attribute__((ext_vector_type(4))) float f32x4;
typedef __attribute__((ext_vector_type(2))) unsigned u32x2;

#define LOG2E 1.4426950408889634f

// ws layout (bytes)
#define WT_OFF   0                                  // 3*128*128 bf16 = 96 KB
#define WSS_OFF  (1u<<20)                           // 2 MB
#define WSP_OFF  ((1u<<20) + NB*NCHUNK*CD*4)
#define POOL_OFF ((1u<<20) + 2u*NB*NCHUNK*CD*4)
#define WSQ_OFF  (8u<<20)                           // 64 MB bf16 sig(q), [n][d][l]

__device__ __forceinline__ unsigned short f2bf(float f) {
    union { float f; unsigned u; } v; v.f = f;
    unsigned r = v.u + 0x7FFFu + ((v.u >> 16) & 1u);
    return (unsigned short)(r >> 16);
}
__device__ __forceinline__ float bf2f(unsigned short h) {
    union { unsigned u; float f; } v; v.u = ((unsigned)h) << 16;
    return v.f;
}
__device__ __forceinline__ unsigned pack2(float lo, float hi) {
    union { __hip_bfloat162 h; unsigned u; } v;
    v.h = __float22bfloat162_rn(float2{lo, hi});   // v_cvt_pk_bf16_f32
    return v.u;
}

// asm loads: results cannot be rematerialized -> guaranteed VGPR residency
__device__ __forceinline__ short8 gload16(const void* p) {
    short8 d;
    unsigned long long a = (unsigned long long)p;
    asm volatile("global_load_dwordx4 %0, %1, off" : "=&v"(d) : "v"(a));
    return d;
}
__device__ __forceinline__ float gload4(const void* p) {
    float d;
    unsigned long long a = (unsigned long long)p;
    asm volatile("global_load_dword %0, %1, off" : "=&v"(d) : "v"(a));
    return d;
}

// W[t] is [C=128][D=128]; produce wt[t][d][c] = bf16(W[c][d])  (c contiguous)
__global__ void prep_wt(const float* __restrict__ Wq, const float* __restrict__ Wk,
                        const float* __restrict__ Wv, unsigned short* __restrict__ wt) {
    int t = blockIdx.x >> 7;
    int d = blockIdx.x & 127;
    const float* W = (t == 0) ? Wq : (t == 1) ? Wk : Wv;
    int c = threadIdx.x;
    wt[((size_t)t*CD + d)*CD + c] = f2bf(W[c*CD + d]);
}

// ---- pass 1: fused Q,K,V GEMM on one 64-l chunk; 8 waves x 16 d each ----
// LDS x: element (l,c) at byte 272*l + 16*((c>>3) ^ ((l>>2)&7)) + (c&7)*2
// A = x fragment (rows = l), B = wt row (cols = d). acc[v] <-> (l = l0+16lt+4g+v, d = 16ww+r)
__global__ __launch_bounds__(512, 1)
void aft_qkv(const float* __restrict__ x, const unsigned short* __restrict__ wt,
             const float* __restrict__ bq, const float* __restrict__ bk,
             const float* __restrict__ bv,
             float* __restrict__ wsS, float* __restrict__ wsP,
             unsigned short* __restrict__ wsq) {
    __shared__ char lds_x[64 * 272];
    const int tid = threadIdx.x;
    const int n = blockIdx.x >> 6;
    const int ch = blockIdx.x & 63;
    const int l0 = ch * LCHUNK;
    const int ww = tid >> 6, lane = tid & 63, r = lane & 15, g = lane >> 4;

    // ---- B-fragments via asm loads (issued first; drained by the barrier) ----
    const int d = 16*ww + r;
    short8 b_q[4], b_k[4], b_v[4];
#pragma unroll
    for (int s = 0; s < 4; ++s) {
        b_q[s] = gload16(wt + ((size_t)(0*CD + d))*CD + 32*s + 8*g);
        b_k[s] = gload16(wt + ((size_t)(1*CD + d))*CD + 32*s + 8*g);
        b_v[s] = gload16(wt + ((size_t)(2*CD + d))*CD + 32*s + 8*g);
    }
    const float bql = gload4(bq + d), bkl = gload4(bk + d), bvl = gload4(bv + d);

    // ---- stage x[n][:, l0:l0+64] -> swizzled LDS bf16 (512 thr: 2 c-pairs each) ----
    {
        const int f = tid & 15, tg = tid >> 4;     // f: l-quad, tg: 0..31 c-pair group
#pragma unroll
        for (int it = 0; it < 2; ++it) {
            int cp = tg + 32*it;                   // c-pair 0..63
            f32x4 lo = *(const f32x4*)(x + ((size_t)n*CD + 2*cp    )*LL + l0 + 4*f);
            f32x4 hi = *(const f32x4*)(x + ((size_t)n*CD + 2*cp + 1)*LL + l0 + 4*f);
            char* base = lds_x + (4*f)*272 + 16*((cp >> 2) ^ (f & 7)) + 4*(cp & 3);
#pragma unroll
            for (int j = 0; j < 4; ++j)
                *(unsigned*)(base + j*272) = pack2(lo[j], hi[j]);
        }
    }

    __syncthreads();   // drains vmcnt(0): asm weight loads complete here

    float s_run = 0.f, p_run = 0.f;

#pragma unroll
    for (int lt = 0; lt < 4; ++lt) {
        const int lrow = 16*lt + r;
        const int lsw = (lrow >> 2) & 7;
        short8 a[4];
#pragma unroll
        for (int s = 0; s < 4; ++s)
            a[s] = *(const short8*)(lds_x + lrow*272 + 16*((4*s + g) ^ lsw));
        f32x4 aq = (f32x4){0,0,0,0};
        f32x4 ak = (f32x4){0,0,0,0};
        f32x4 av = (f32x4){0,0,0,0};
#pragma unroll
        for (int s = 0; s < 4; ++s) {
            aq = __builtin_amdgcn_mfma_f32_16x16x32_bf16(a[s], b_q[s], aq, 0,0,0);
            ak = __builtin_amdgcn_mfma_f32_16x16x32_bf16(a[s], b_k[s], ak, 0,0,0);
            av = __builtin_amdgcn_mfma_f32_16x16x32_bf16(a[s], b_v[s], av, 0,0,0);
        }
        float sg[4];
#pragma unroll
        for (int v = 0; v < 4; ++v) {
            float e = __builtin_amdgcn_exp2f((ak[v] + bkl) * LOG2E);
            s_run += e;
            p_run += e * (av[v] + bvl);
            float q2 = (aq[v] + bql) * LOG2E;
            sg[v] = __builtin_amdgcn_rcpf(1.f + __builtin_amdgcn_exp2f(-q2));
        }
        u32x2 val = { pack2(sg[0], sg[1]), pack2(sg[2], sg[3]) };
        // 8B store at (d, l = l0+16lt+4g); lt x g covers the full 64-l chunk
        *(u32x2*)(wsq + ((size_t)n*CD + d)*LL + l0 + 16*lt + 4*g) = val;
    }

    // ---- reduce (s,p) over the 4 g-lanes; lane g==0 writes d ----
    s_run += __shfl_xor(s_run, 16, 64);  p_run += __shfl_xor(p_run, 16, 64);
    s_run += __shfl_xor(s_run, 32, 64);  p_run += __shfl_xor(p_run, 32, 64);
    if (g == 0) {
        size_t idx = ((size_t)n*NCHUNK + ch)*CD + d;
        wsS[idx] = s_run;
        wsP[idx] = p_run;
    }
}

// ---------------- pass 2: combine partials -> pooled[n][d] ----------------
__global__ void aft_pass2(const float* __restrict__ wsS, const float* __restrict__ wsP,
                          float* __restrict__ pooled) {
    int n = blockIdx.x, d = threadIdx.x;
    float s = 0.f, p = 0.f;
    for (int b = 0; b < NCHUNK; ++b) {
        size_t idx = ((size_t)n*NCHUNK + b)*CD + d;
        s += wsS[idx];
        p += wsP[idx];
    }
    pooled[(size_t)n*CD + d] = p / s;
}

// ---- pass 3: out[n][d][l] = bf2f(wsq[n][d][l]) * pooled[n][d], pure streaming ----
__global__ __launch_bounds__(256)
void aft_pass3(const unsigned short* __restrict__ wsq, const float* __restrict__ pooled,
               float* __restrict__ out) {
    const int b = blockIdx.x;
    const int n = b >> 8;
    const int d = (b >> 1) & 127;
    const int half = b & 1;
    const float pl = pooled[(size_t)n*CD + d];
    const size_t base = ((size_t)n*CD + d)*LL + half*2048 + threadIdx.x*8;
    short8 v = *(const short8*)(wsq + base);
    f32x4 o0, o1;
#pragma unroll
    for (int j = 0; j < 4; ++j) {
        o0[j] = bf2f((unsigned short)v[j]) * pl;
        o1[j] = bf2f((unsigned short)v[4+j]) * pl;
    }
    *(f32x4*)(out + base) = o0;
    *(f32x4*)(out + base + 4) = o1;
}

extern "C" void kernel_launch(void* const* d_in, const int* in_sizes, int n_in,
                              void* d_out, int out_size, void* d_ws, size_t ws_size,
                              hipStream_t stream) {
    const float* x  = (const float*)d_in[0];
    const float* Wq = (const float*)d_in[1];
    const float* bq = (const float*)d_in[2];
    const float* Wk = (const float*)d_in[3];
    const float* bk = (const float*)d_in[4];
    const float* Wv = (const float*)d_in[5];
    const float* bv = (const float*)d_in[6];
    float* out = (float*)d_out;
    char* ws = (char*)d_ws;
    unsigned short* wt = (unsigned short*)(ws + WT_OFF);
    float* wsS = (float*)(ws + WSS_OFF);
    float* wsP = (float*)(ws + WSP_OFF);
    float* pooled = (float*)(ws + POOL_OFF);
    unsigned short* wsq = (unsigned short*)(ws + WSQ_OFF);

    prep_wt<<<384, 128, 0, stream>>>(Wq, Wk, Wv, wt);
    aft_qkv<<<NB * NCHUNK, 512, 0, stream>>>(x, wt, bq, bk, bv, wsS, wsP, wsq);
    aft_pass2<<<NB, CD, 0, stream>>>(wsS, wsP, pooled);
    aft_pass3<<<NB * CD * 2, 256, 0, stream>>>(wsq, pooled, out);
}

// Round 11
// 109.576 us; speedup vs baseline: 1.2613x; 1.2613x over previous
//
#include <hip/hip_runtime.h>
#include <hip/hip_bf16.h>

#define NB 64
#define CD 128
#define LL 4096
#define LCHUNK 64
#define NCHUNK 64      // LL/LCHUNK
#define NBG 16         // block-groups per n
#define CPB 4          // chunks per block

typedef __attribute__((ext_vector_type(8))) short short8;
typedef __attribute__((ext_vector_type(4))) float f32x4;
typedef __attribute__((ext_vector_type(2))) unsigned u32x2;
typedef __attribute__((ext_vector_type(4))) unsigned u32x4;

#define LOG2E 1.4426950408889634f

// ws layout (bytes)
#define WT_OFF   0                                  // 3*128*128 bf16 = 96 KB
#define WSS_OFF  (1u<<20)
#define WSP_OFF  ((1u<<20) + NB*NBG*CD*4)
#define POOL_OFF ((1u<<20) + 2u*NB*NBG*CD*4)
#define WSQ_OFF  (8u<<20)                           // 64 MB bf16 sig(q), [n][d][l]

__device__ __forceinline__ unsigned short f2bf(float f) {
    union { float f; unsigned u; } v; v.f = f;
    unsigned r = v.u + 0x7FFFu + ((v.u >> 16) & 1u);
    return (unsigned short)(r >> 16);
}
__device__ __forceinline__ float bf2f(unsigned short h) {
    union { unsigned u; float f; } v; v.u = ((unsigned)h) << 16;
    return v.f;
}
__device__ __forceinline__ unsigned pack2(float lo, float hi) {
    union { __hip_bfloat162 h; unsigned u; } v;
    v.h = __float22bfloat162_rn(float2{lo, hi});   // v_cvt_pk_bf16_f32
    return v.u;
}

// W[t] is [C=128][D=128]; produce wt[t][d][c] = bf16(W[c][d])  (c contiguous)
__global__ void prep_wt(const float* __restrict__ Wq, const float* __restrict__ Wk,
                        const float* __restrict__ Wv, unsigned short* __restrict__ wt) {
    int t = blockIdx.x >> 7;
    int d = blockIdx.x & 127;
    const float* W = (t == 0) ? Wq : (t == 1) ? Wk : Wv;
    int c = threadIdx.x;
    wt[((size_t)t*CD + d)*CD + c] = f2bf(W[c*CD + d]);
}

// ---- pass 1: fused QKV GEMM, ALL MFMA operands from LDS (m97 pattern) ----
// lds_w: row = t*128+d (256 B = 128 c); 16B-block b holds c=8b..8b+7 at
//        byte 256*row + 16*(b ^ (row&7)).  Read: lane(r,g) wants b=4s+g at row d
//        -> bank-quad ((4s+g)^(r&7))&7: 8 lanes/quad = 2/bank = free.
// lds_x: element (l,c) at 272*l + 16*((c>>3)^((l>>2)&7)) + (c&7)*2  (R3-verified).
// Wave ww: d-group dgi=ww&7 (d=16*dgi+r), l-half lh=ww>>3 (lt = 2lh, 2lh+1).
// acc[v] <-> (l = l0+16*lt+4g+v, d).
__global__ __launch_bounds__(1024) __attribute__((amdgpu_waves_per_eu(4, 4)))
void aft_qkv(const float* __restrict__ x, const unsigned short* __restrict__ wt,
             const float* __restrict__ bq, const float* __restrict__ bk,
             const float* __restrict__ bv,
             float* __restrict__ wsS, float* __restrict__ wsP,
             unsigned short* __restrict__ wsq) {
    __shared__ char lds[98304 + 17408];      // 113 KB: weights + x chunk
    char* lds_w = lds;
    char* lds_x = lds + 98304;
    const int tid = threadIdx.x;
    const int n = blockIdx.x >> 4;
    const int bg = blockIdx.x & 15;
    const int ww = tid >> 6, lane = tid & 63, r = lane & 15, g = lane >> 4;
    const int dgi = ww & 7, lh = ww >> 3;
    const int d = 16*dgi + r;

    // ---- stage all weights into LDS (once; 6144 16B blocks, coalesced) ----
#pragma unroll
    for (int k = 0; k < 6; ++k) {
        int bi = tid + 1024*k;
        u32x4 v = *(const u32x4*)((const char*)wt + (size_t)bi*16);
        *(u32x4*)(lds_w + 256*(bi >> 4) + 16*((bi & 15) ^ ((bi >> 4) & 7))) = v;
    }

    const float bql = bq[d], bkl = bk[d], bvl = bv[d];
    float s_run = 0.f, p_run = 0.f;

#pragma unroll 1
    for (int t = 0; t < CPB; ++t) {
        const int l0 = (bg*CPB + t) * LCHUNK;
        __syncthreads();   // lds_x free (and, at t=0, weights staged)
        // ---- stage x[n][:, l0:l0+64]: 1024 thr, 32 B each ----
        {
            const int f = tid & 15, cp = tid >> 4;   // f: l-quad, cp: c-pair 0..63
            f32x4 lo = *(const f32x4*)(x + ((size_t)n*CD + 2*cp    )*LL + l0 + 4*f);
            f32x4 hi = *(const f32x4*)(x + ((size_t)n*CD + 2*cp + 1)*LL + l0 + 4*f);
            char* base = lds_x + (4*f)*272 + 16*((cp >> 2) ^ (f & 7)) + 4*(cp & 3);
#pragma unroll
            for (int j = 0; j < 4; ++j)
                *(unsigned*)(base + j*272) = pack2(lo[j], hi[j]);
        }
        __syncthreads();

        // ---- compute: every operand via ds_read ----
        f32x4 aq[2], ak[2], av[2];
#pragma unroll
        for (int j = 0; j < 2; ++j) {
            aq[j] = (f32x4){0,0,0,0};
            ak[j] = (f32x4){0,0,0,0};
            av[j] = (f32x4){0,0,0,0};
        }
#pragma unroll
        for (int s = 0; s < 4; ++s) {
            const int wb = 16*((4*s + g) ^ (r & 7));
            short8 wqf = *(const short8*)(lds_w +         256*d + wb);
            short8 wkf = *(const short8*)(lds_w + 32768 + 256*d + wb);
            short8 wvf = *(const short8*)(lds_w + 65536 + 256*d + wb);
#pragma unroll
            for (int j = 0; j < 2; ++j) {
                const int lrow = 16*(2*lh + j) + r;
                short8 a = *(const short8*)(lds_x + 272*lrow + 16*((4*s + g) ^ ((lrow >> 2) & 7)));
                aq[j] = __builtin_amdgcn_mfma_f32_16x16x32_bf16(a, wqf, aq[j], 0,0,0);
                ak[j] = __builtin_amdgcn_mfma_f32_16x16x32_bf16(a, wkf, ak[j], 0,0,0);
                av[j] = __builtin_amdgcn_mfma_f32_16x16x32_bf16(a, wvf, av[j], 0,0,0);
            }
        }
        // ---- tail: fold (s,p), sigmoid(q) -> wsq ----
#pragma unroll
        for (int j = 0; j < 2; ++j) {
            float sg[4];
#pragma unroll
            for (int v = 0; v < 4; ++v) {
                float e = __builtin_amdgcn_exp2f((ak[j][v] + bkl) * LOG2E);
                s_run += e;
                p_run += e * (av[j][v] + bvl);
                float q2 = (aq[j][v] + bql) * LOG2E;
                sg[v] = __builtin_amdgcn_rcpf(1.f + __builtin_amdgcn_exp2f(-q2));
            }
            u32x2 val = { pack2(sg[0], sg[1]), pack2(sg[2], sg[3]) };
            *(u32x2*)(wsq + ((size_t)n*CD + d)*LL + l0 + 16*(2*lh + j) + 4*g) = val;
        }
    }

    // ---- tail reduce: g-lanes, then l-halves via LDS (aliases dead lds_x) ----
    __syncthreads();
    float* redS = (float*)(lds + 98304);
    float* redP = redS + 16*CD;
    s_run += __shfl_xor(s_run, 16, 64);  p_run += __shfl_xor(p_run, 16, 64);
    s_run += __shfl_xor(s_run, 32, 64);  p_run += __shfl_xor(p_run, 32, 64);
    if (g == 0) {
        redS[ww*CD + d] = s_run;
        redP[ww*CD + d] = p_run;
    }
    __syncthreads();
    if (tid < CD) {
        int w0 = tid >> 4;
        float s = redS[w0*CD + tid] + redS[(w0 + 8)*CD + tid];
        float p = redP[w0*CD + tid] + redP[(w0 + 8)*CD + tid];
        size_t idx = ((size_t)n*NBG + bg)*CD + tid;
        wsS[idx] = s;
        wsP[idx] = p;
    }
}

// ---------------- pass 2: combine partials -> pooled[n][d] ----------------
__global__ void aft_pass2(const float* __restrict__ wsS, const float* __restrict__ wsP,
                          float* __restrict__ pooled) {
    int n = blockIdx.x, d = threadIdx.x;
    float s = 0.f, p = 0.f;
    for (int b = 0; b < NBG; ++b) {
        size_t idx = ((size_t)n*NBG + b)*CD + d;
        s += wsS[idx];
        p += wsP[idx];
    }
    pooled[(size_t)n*CD + d] = p / s;
}

// ---- pass 3: out[n][d][l] = bf2f(wsq[n][d][l]) * pooled[n][d], pure streaming ----
__global__ __launch_bounds__(256)
void aft_pass3(const unsigned short* __restrict__ wsq, const float* __restrict__ pooled,
               float* __restrict__ out) {
    const int b = blockIdx.x;
    const int n = b >> 8;
    const int d = (b >> 1) & 127;
    const int half = b & 1;
    const float pl = pooled[(size_t)n*CD + d];
    const size_t base = ((size_t)n*CD + d)*LL + half*2048 + threadIdx.x*8;
    short8 v = *(const short8*)(wsq + base);
    f32x4 o0, o1;
#pragma unroll
    for (int j = 0; j < 4; ++j) {
        o0[j] = bf2f((unsigned short)v[j]) * pl;
        o1[j] = bf2f((unsigned short)v[4+j]) * pl;
    }
    *(f32x4*)(out + base) = o0;
    *(f32x4*)(out + base + 4) = o1;
}

extern "C" void kernel_launch(void* const* d_in, const int* in_sizes, int n_in,
                              void* d_out, int out_size, void* d_ws, size_t ws_size,
                              hipStream_t stream) {
    const float* x  = (const float*)d_in[0];
    const float* Wq = (const float*)d_in[1];
    const float* bq = (const float*)d_in[2];
    const float* Wk = (const float*)d_in[3];
    const float* bk = (const float*)d_in[4];
    const float* Wv = (const float*)d_in[5];
    const float* bv = (const float*)d_in[6];
    float* out = (float*)d_out;
    char* ws = (char*)d_ws;
    unsigned short* wt = (unsigned short*)(ws + WT_OFF);
    float* wsS = (float*)(ws + WSS_OFF);
    float* wsP = (float*)(ws + WSP_OFF);
    float* pooled = (float*)(ws + POOL_OFF);
    unsigned short* wsq = (unsigned short*)(ws + WSQ_OFF);

    prep_wt<<<384, 128, 0, stream>>>(Wq, Wk, Wv, wt);
    aft_qkv<<<NB * NBG, 1024, 0, stream>>>(x, wt, bq, bk, bv, wsS, wsP, wsq);
    aft_pass2<<<NB, CD, 0, stream>>>(wsS, wsP, pooled);
    aft_pass3<<<NB * CD * 2, 256, 0, stream>>>(wsq, pooled, out);
}

// Round 12
// 102.488 us; speedup vs baseline: 1.3485x; 1.0692x over previous
//
#include <hip/hip_runtime.h>
#include <hip/hip_bf16.h>

#define NB 64
#define CD 128
#define LL 4096
#define LCHUNK 64
#define NCHUNK 64      // LL/LCHUNK
#define NBG 8          // blocks per n
#define CPB 8          // chunks per block

typedef __attribute__((ext_vector_type(8))) short short8;
typedef __attribute__((ext_vector_type(4))) float f32x4;
typedef __attribute__((ext_vector_type(16))) float f32x16;
typedef __attribute__((ext_vector_type(2))) unsigned u32x2;
typedef __attribute__((ext_vector_type(4))) unsigned u32x4;

#define LOG2E 1.4426950408889634f

// ws layout (bytes)
#define WT_OFF   0                                  // 3*128*128 bf16 = 96 KB
#define WSS_OFF  (1u<<20)
#define WSP_OFF  ((1u<<20) + NB*NBG*CD*4)
#define POOL_OFF ((1u<<20) + 2u*NB*NBG*CD*4)
#define WSQ_OFF  (8u<<20)                           // 64 MB bf16 sig(q), [n][d][l]

__device__ __forceinline__ unsigned short f2bf(float f) {
    union { float f; unsigned u; } v; v.f = f;
    unsigned r = v.u + 0x7FFFu + ((v.u >> 16) & 1u);
    return (unsigned short)(r >> 16);
}
__device__ __forceinline__ float bf2f(unsigned short h) {
    union { unsigned u; float f; } v; v.u = ((unsigned)h) << 16;
    return v.f;
}
__device__ __forceinline__ unsigned pack2(float lo, float hi) {
    union { __hip_bfloat162 h; unsigned u; } v;
    v.h = __float22bfloat162_rn(float2{lo, hi});   // v_cvt_pk_bf16_f32
    return v.u;
}
// asm load: issue point pinned in program order (prefetch cannot be sunk)
__device__ __forceinline__ f32x4 gload16f(const float* p) {
    f32x4 d;
    asm volatile("global_load_dwordx4 %0, %1, off"
                 : "=&v"(d) : "v"((unsigned long long)(uintptr_t)p));
    return d;
}

// W[t] is [C=128][D=128]; produce wt[t][d][c] = bf16(W[c][d])  (c contiguous)
__global__ void prep_wt(const float* __restrict__ Wq, const float* __restrict__ Wk,
                        const float* __restrict__ Wv, unsigned short* __restrict__ wt) {
    int t = blockIdx.x >> 7;
    int d = blockIdx.x & 127;
    const float* W = (t == 0) ? Wq : (t == 1) ? Wk : Wv;
    int c = threadIdx.x;
    wt[((size_t)t*CD + d)*CD + c] = f2bf(W[c*CD + d]);
}

// x-chunk LDS image: element (l,c) at byte 272*l + 16*((c>>3) ^ ((l>>2)&7)) + (c&7)*2
__device__ __forceinline__ void stage_x_write(char* bufx, int f, int cp, f32x4 lo, f32x4 hi) {
    char* base = bufx + (4*f)*272 + 16*((cp >> 2) ^ (f & 7)) + 4*(cp & 3);
#pragma unroll
    for (int j = 0; j < 4; ++j)
        *(unsigned*)(base + j*272) = pack2(lo[j], hi[j]);
}

// ---- pass 1: fused QKV GEMM, 32x32x16 MFMA, weights in LDS, x double-buffered ----
// lds_w: row R = t*128+d (256 B); 16B-block b at byte 256*R + 16*(b ^ (R&7)).
// Wave ww: lh = ww&1 (l-half of chunk), ng = ww>>1 (32-d group).
// Lane: u = lane&31, h = lane>>5. A row l = 32*lh+u; B col d = 32*ng+u.
// acc reg -> (l = l0+32*lh+(reg&3)+8*(reg>>2)+4*h, d)  [C/D map m74/m101]
__global__ __launch_bounds__(512)
void aft_qkv(const float* __restrict__ x, const unsigned short* __restrict__ wt,
             const float* __restrict__ bq, const float* __restrict__ bk,
             const float* __restrict__ bv,
             float* __restrict__ wsS, float* __restrict__ wsP,
             unsigned short* __restrict__ wsq) {
    __shared__ char lds_w[98304];
    __shared__ char lds_x[2][17408];
    __shared__ float red_s[4][32];
    __shared__ float red_p[4][32];
    const int tid = threadIdx.x;
    const int n = blockIdx.x >> 3;
    const int bg = blockIdx.x & 7;
    const int ww = tid >> 6, lane = tid & 63;
    const int u = lane & 31, h = lane >> 5;
    const int lh = ww & 1, ng = ww >> 1;
    const int d = 32*ng + u;
    const int f = tid & 15, tg = tid >> 4;   // staging: f = l-quad, tg = c-pair group

    // ---- stage all weights into LDS (once per block; 96 KB from L2) ----
#pragma unroll
    for (int k = 0; k < 12; ++k) {
        int bi = tid + 512*k;                // 16B block index 0..6143
        u32x4 v = *(const u32x4*)((const char*)wt + (size_t)bi*16);
        *(u32x4*)(lds_w + 256*(bi >> 4) + 16*((bi & 15) ^ ((bi >> 4) & 7))) = v;
    }
    // ---- stage x chunk 0 ----
    {
        const int l0 = bg*CPB*LCHUNK;
#pragma unroll
        for (int it = 0; it < 2; ++it) {
            int cp = tg + 32*it;
            f32x4 lo = *(const f32x4*)(x + ((size_t)n*CD + 2*cp    )*LL + l0 + 4*f);
            f32x4 hi = *(const f32x4*)(x + ((size_t)n*CD + 2*cp + 1)*LL + l0 + 4*f);
            stage_x_write(lds_x[0], f, cp, lo, hi);
        }
    }
    const float bql = bq[d], bkl = bk[d], bvl = bv[d];
    float s_run = 0.f, p_run = 0.f;
    __syncthreads();

#pragma unroll 1
    for (int t = 0; t < CPB; ++t) {
        const int l0 = (bg*CPB + t) * LCHUNK;
        // ---- prefetch next chunk's x to registers (asm: issue pinned here) ----
        f32x4 pf0, pf1, pf2, pf3;
        if (t + 1 < CPB) {
            const float* xb = x + (size_t)n*CD*LL + (l0 + LCHUNK) + 4*f;
            pf0 = gload16f(xb + (size_t)(2*tg     )*LL);
            pf1 = gload16f(xb + (size_t)(2*tg + 1 )*LL);
            pf2 = gload16f(xb + (size_t)(2*(tg+32)    )*LL);
            pf3 = gload16f(xb + (size_t)(2*(tg+32) + 1)*LL);
        }
        // ---- compute: 8 k-steps, A read once feeds Q,K,V ----
        const char* abase = lds_x[t & 1] + 272*(32*lh + u);
        const int asw = ((32*lh + u) >> 2) & 7;
        const char* wb = lds_w + 256*d;
        const int dsw = d & 7;
        f32x16 aq = {0,0,0,0,0,0,0,0,0,0,0,0,0,0,0,0};
        f32x16 ak = {0,0,0,0,0,0,0,0,0,0,0,0,0,0,0,0};
        f32x16 av = {0,0,0,0,0,0,0,0,0,0,0,0,0,0,0,0};
#pragma unroll
        for (int kk = 0; kk < 8; ++kk) {
            const int cb = 2*kk + h;
            short8 a   = *(const short8*)(abase + 16*(cb ^ asw));
            short8 wqf = *(const short8*)(wb           + 16*(cb ^ dsw));
            short8 wkf = *(const short8*)(wb + 32768   + 16*(cb ^ dsw));
            short8 wvf = *(const short8*)(wb + 65536   + 16*(cb ^ dsw));
            aq = __builtin_amdgcn_mfma_f32_32x32x16_bf16(a, wqf, aq, 0,0,0);
            ak = __builtin_amdgcn_mfma_f32_32x32x16_bf16(a, wkf, ak, 0,0,0);
            av = __builtin_amdgcn_mfma_f32_32x32x16_bf16(a, wvf, av, 0,0,0);
        }
        // ---- epilogue: (s,p) fold + sigmoid(q) -> wsq (per lane: fixed d, 16 l) ----
#pragma unroll
        for (int grp = 0; grp < 4; ++grp) {
            float sg[4];
#pragma unroll
            for (int e = 0; e < 4; ++e) {
                const int reg = 4*grp + e;
                float ex = __builtin_amdgcn_exp2f((ak[reg] + bkl) * LOG2E);
                s_run += ex;
                p_run += ex * (av[reg] + bvl);
                float q2 = (aq[reg] + bql) * LOG2E;
                sg[e] = __builtin_amdgcn_rcpf(1.f + __builtin_amdgcn_exp2f(-q2));
            }
            u32x2 val = { pack2(sg[0], sg[1]), pack2(sg[2], sg[3]) };
            *(u32x2*)(wsq + ((size_t)n*CD + d)*LL + l0 + 32*lh + 8*grp + 4*h) = val;
        }
        // ---- drain prefetch, write next chunk to other buffer ----
        if (t + 1 < CPB) {
            asm volatile("s_waitcnt vmcnt(0)" ::: "memory");
            __builtin_amdgcn_sched_barrier(0);
            char* nb = lds_x[(t + 1) & 1];
            stage_x_write(nb, f, tg,      pf0, pf1);
            stage_x_write(nb, f, tg + 32, pf2, pf3);
        }
        __syncthreads();
    }

    // ---- block-level (s,p) reduce: lane pairs (u, u+32), then the 2 lh waves ----
    s_run += __shfl_xor(s_run, 32, 64);
    p_run += __shfl_xor(p_run, 32, 64);
    if (lh == 1 && h == 0) { red_s[ng][u] = s_run; red_p[ng][u] = p_run; }
    __syncthreads();
    if (lh == 0 && h == 0) {
        size_t idx = ((size_t)n*NBG + bg)*CD + d;
        wsS[idx] = s_run + red_s[ng][u];
        wsP[idx] = p_run + red_p[ng][u];
    }
}

// ---------------- pass 2: combine partials -> pooled[n][d] ----------------
__global__ void aft_pass2(const float* __restrict__ wsS, const float* __restrict__ wsP,
                          float* __restrict__ pooled) {
    int n = blockIdx.x, d = threadIdx.x;
    float s = 0.f, p = 0.f;
    for (int b = 0; b < NBG; ++b) {
        size_t idx = ((size_t)n*NBG + b)*CD + d;
        s += wsS[idx];
        p += wsP[idx];
    }
    pooled[(size_t)n*CD + d] = p / s;
}

// ---- pass 3: out[n][d][l] = bf2f(wsq[n][d][l]) * pooled[n][d], pure streaming ----
__global__ __launch_bounds__(256)
void aft_pass3(const unsigned short* __restrict__ wsq, const float* __restrict__ pooled,
               float* __restrict__ out) {
    const int b = blockIdx.x;
    const int n = b >> 8;
    const int d = (b >> 1) & 127;
    const int half = b & 1;
    const float pl = pooled[(size_t)n*CD + d];
    const size_t base = ((size_t)n*CD + d)*LL + half*2048 + threadIdx.x*8;
    short8 v = *(const short8*)(wsq + base);
    f32x4 o0, o1;
#pragma unroll
    for (int j = 0; j < 4; ++j) {
        o0[j] = bf2f((unsigned short)v[j]) * pl;
        o1[j] = bf2f((unsigned short)v[4+j]) * pl;
    }
    *(f32x4*)(out + base) = o0;
    *(f32x4*)(out + base + 4) = o1;
}

extern "C" void kernel_launch(void* const* d_in, const int* in_sizes, int n_in,
                              void* d_out, int out_size, void* d_ws, size_t ws_size,
                              hipStream_t stream) {
    const float* x  = (const float*)d_in[0];
    const float* Wq = (const float*)d_in[1];
    const float* bq = (const float*)d_in[2];
    const float* Wk = (const float*)d_in[3];
    const float* bk = (const float*)d_in[4];
    const float* Wv = (const float*)d_in[5];
    const float* bv = (const float*)d_in[6];
    float* out = (float*)d_out;
    char* ws = (char*)d_ws;
    unsigned short* wt = (unsigned short*)(ws + WT_OFF);
    float* wsS = (float*)(ws + WSS_OFF);
    float* wsP = (float*)(ws + WSP_OFF);
    float* pooled = (float*)(ws + POOL_OFF);
    unsigned short* wsq = (unsigned short*)(ws + WSQ_OFF);

    prep_wt<<<384, 128, 0, stream>>>(Wq, Wk, Wv, wt);
    aft_qkv<<<NB * NBG, 512, 0, stream>>>(x, wt, bq, bk, bv, wsS, wsP, wsq);
    aft_pass2<<<NB, CD, 0, stream>>>(wsS, wsP, pooled);
    aft_pass3<<<NB * CD * 2, 256, 0, stream>>>(wsq, pooled, out);
}